// Round 2
// baseline (148.954 us; speedup 1.0000x reference)
//
#include <hip/hip_runtime.h>
#include <stdint.h>

typedef float    f32x4 __attribute__((ext_vector_type(4)));
typedef uint32_t u32x4 __attribute__((ext_vector_type(4)));

// Soft-logic FP32 adder circuit, emulated exactly in integer arithmetic on the
// packed 32-bit word. Bit p in memory (p=0 sign, 1..8 exp MSB..LSB, 9..31 mant
// MSB..LSB) maps to IEEE bit (31-p) of the packed word.
// (Verified bit-exact vs reference in round 1: absmax 0.)
__device__ __forceinline__ uint32_t soft_fp32_add(uint32_t aw, uint32_t bw) {
    const uint32_t M28 = 0x0FFFFFFFu;
    uint32_t sa = aw >> 31, sb = bw >> 31;
    uint32_t ea = (aw >> 23) & 0xFFu, eb = (bw >> 23) & 0xFFu;
    uint32_t ma = aw & 0x7FFFFFu,     mb = bw & 0x7FFFFFu;
    uint32_t ha = (ea != 0u) ? 1u : 0u, hb = (eb != 0u) ? 1u : 0u;
    uint32_t eaf = ha ? ea : 1u;                 // effective exponent (subnormal -> 1)
    uint32_t ebf = hb ? eb : 1u;
    uint32_t mA = (ha << 27) | (ma << 4);        // 28-bit: hidden | mant | 4 guard zeros
    uint32_t mB = (hb << 27) | (mb << 4);
    // magnitude compare, lexicographic on (e_eff, hidden|mant)
    uint32_t keyA = (eaf << 24) | (ha << 23) | ma;
    uint32_t keyB = (ebf << 24) | (hb << 23) | mb;
    uint32_t age  = (keyA >= keyB) ? 1u : 0u;    // a_ge_b
    uint32_t abeq = (keyA == keyB) ? 1u : 0u;    // |A| == |B|
    uint32_t ediff = age ? (eaf - ebf) : (ebf - eaf);   // nonnegative by selection
    uint32_t big = (ediff >= 24u) ? 1u : 0u;     // is_big_diff (bits>=32 or (b4&b3))
    uint32_t sh  = ediff & 31u;                  // shift_amt = low 5 bits
    uint32_t emax = age ? eaf : ebf;
    uint32_t ml   = age ? mA : mB;
    uint32_t msu  = age ? mB : mA;               // m_small unshifted
    uint32_t ms     = msu >> sh;
    uint32_t sticky = ((msu & ((1u << sh) - 1u)) != 0u) ? 1u : 0u;
    if (big) { ms = 0u; sticky = (msu != 0u) ? 1u : 0u; }
    uint32_t dsgn   = sa ^ sb;                   // is_diff_sign
    uint32_t cancel = dsgn & abeq;               // exact_cancel
    uint32_t sl     = age ? sa : sb;             // s_large
    uint32_t sum    = ml + ms;                   // 29-bit
    uint32_t scarry = sum >> 28;
    uint32_t sres   = sum & M28;
    uint32_t diff   = (ml - ms) & M28;
    uint32_t dfin   = (dsgn & sticky) ? ((diff - 1u) & M28) : diff;  // need_sub_one
    uint32_t mant   = dsgn ? dfin : sres;        // mant_res
    uint32_t rc     = dsgn ? 0u : scarry;        // result_carry
    uint32_t lzc    = mant ? (uint32_t)(__clz((int)mant) - 4) : 28u; // lzd28
    uint32_t undf   = (lzc >= emax) ? 1u : 0u;   // is_underflow (lzc8 >= e_max)
    uint32_t norm   = (mant << lzc) & M28;       // barrel_left
    uint32_t e_aft  = (emax - lzc) & 0xFFu;      // 8-bit wrap
    uint32_t e_p1   = (emax + 1u) & 0xFFu;
    uint32_t e_nrm  = undf ? 0u : e_aft;
    uint32_t fe     = rc ? e_p1 : e_nrm;         // final_e_pre
    uint32_t m_ovf  = mant >> 5;                 // bits 0..22  (also == m_subnorm)
    uint32_t r_ovf  = (mant >> 4) & 1u;          // bit 23
    uint32_t st_ovf = ((mant & 0xFu) != 0u) ? 1u : 0u;   // bits 24..27
    uint32_t m_nrm  = (norm >> 4) & 0x7FFFFFu;   // bits 1..23
    uint32_t r_nrm  = (norm >> 3) & 1u;          // bit 24
    uint32_t st_nrm = ((norm & 7u) != 0u) ? 1u : 0u;     // bits 25..27
    uint32_t m_pre  = rc ? m_ovf : m_nrm;
    uint32_t r_pre  = rc ? r_ovf : r_nrm;
    uint32_t st_pre = (rc ? st_ovf : st_nrm) | sticky;
    uint32_t m_sel  = undf ? m_ovf : m_pre;      // underflow -> truncated subnormal
    uint32_t Lb     = m_sel & 1u;
    uint32_t dor    = r_pre & (st_pre | Lb) & (undf ^ 1u);   // do_round (RNE)
    uint32_t mr     = m_sel + dor;               // 24-bit
    uint32_t rcar   = mr >> 23;                  // round_carry
    uint32_t m_fin  = mr & 0x7FFFFFu;            // AND(NOT(rcar), rounded) == this
    uint32_t ce     = (fe + rcar) & 0xFFu;       // computed_e
    uint32_t os = cancel ? 0u : sl;
    uint32_t oe = cancel ? 0u : ce;
    uint32_t om = cancel ? 0u : m_fin;
    uint32_t ea1 = (ea == 0xFFu) ? 1u : 0u, eb1 = (eb == 0xFFu) ? 1u : 0u;
    uint32_t manz = (ma != 0u) ? 1u : 0u, mbnz = (mb != 0u) ? 1u : 0u;
    uint32_t anynan = (ea1 & manz) | (eb1 & mbnz);
    uint32_t ainf = ea1 & (manz ^ 1u);
    uint32_t binf = eb1 & (mbnz ^ 1u);
    uint32_t anyinf = ainf | binf;
    uint32_t isnan  = anynan | (dsgn & ainf & binf);
    uint32_t ovf    = (ce == 0xFFu) ? 1u : 0u;   // on computed_e, pre-cancel
    uint32_t out = (os << 31) | (oe << 23) | om;
    if (anyinf | ovf) out = (sl << 31) | (0xFFu << 23);   // inf_res
    if (isnan)        out = (0xFFu << 23) | 0x7FFFFFu;    // nan_res (sign=0)
    return out;
}

// One thread = one row (32 floats = 128 B per input). All 16 input loads are
// independent and issued up-front (deep MLP, no serial load->consume chain,
// no cross-lane ops). Pack: bit = (u>>23)&1 (1.0f has bit 23 set). Stores are
// nontemporal: output is never re-read, keep L2/L3 for the inputs which ARE
// re-read every graph replay.
__global__ __launch_bounds__(256) void SpikeFP32Adder_kernel(
    const uint32_t* __restrict__ A, const uint32_t* __restrict__ B,
    float* __restrict__ O, int nrows)
{
    int row = blockIdx.x * blockDim.x + threadIdx.x;
    if (row >= nrows) return;

    const u32x4* Arow = (const u32x4*)(A + (size_t)row * 32);
    const u32x4* Brow = (const u32x4*)(B + (size_t)row * 32);

    u32x4 a[8], b[8];
    #pragma unroll
    for (int j = 0; j < 8; ++j) a[j] = Arow[j];
    #pragma unroll
    for (int j = 0; j < 8; ++j) b[j] = Brow[j];

    uint32_t aw = 0u, bw = 0u;
    #pragma unroll
    for (int j = 0; j < 8; ++j) {
        const int s = 31 - 4 * j;   // memory bit p=4j..4j+3 -> IEEE bit 31-p
        aw |= ((a[j].x >> 23) & 1u) << s;
        aw |= ((a[j].y >> 23) & 1u) << (s - 1);
        aw |= ((a[j].z >> 23) & 1u) << (s - 2);
        aw |= ((a[j].w >> 23) & 1u) << (s - 3);
        bw |= ((b[j].x >> 23) & 1u) << s;
        bw |= ((b[j].y >> 23) & 1u) << (s - 1);
        bw |= ((b[j].z >> 23) & 1u) << (s - 2);
        bw |= ((b[j].w >> 23) & 1u) << (s - 3);
    }

    uint32_t outw = soft_fp32_add(aw, bw);

    f32x4* Orow = (f32x4*)(O + (size_t)row * 32);
    #pragma unroll
    for (int j = 0; j < 8; ++j) {
        const int s = 31 - 4 * j;
        f32x4 f;
        f.x = (float)((outw >> s) & 1u);
        f.y = (float)((outw >> (s - 1)) & 1u);
        f.z = (float)((outw >> (s - 2)) & 1u);
        f.w = (float)((outw >> (s - 3)) & 1u);
        __builtin_nontemporal_store(f, Orow + j);
    }
}

extern "C" void kernel_launch(void* const* d_in, const int* in_sizes, int n_in,
                              void* d_out, int out_size, void* d_ws, size_t ws_size,
                              hipStream_t stream) {
    const uint32_t* A = (const uint32_t*)d_in[0];
    const uint32_t* B = (const uint32_t*)d_in[1];
    float* O = (float*)d_out;
    int nrows = in_sizes[0] / 32;              // 524288
    int threads = 256;
    int blocks = (nrows + threads - 1) / threads;
    SpikeFP32Adder_kernel<<<dim3(blocks), dim3(threads), 0, stream>>>(A, B, O, nrows);
}

// Round 3
// 37.479 us; speedup vs baseline: 3.9743x; 3.9743x over previous
//
#include <hip/hip_runtime.h>
#include <stdint.h>

typedef float    f32x4 __attribute__((ext_vector_type(4)));
typedef uint32_t u32x4 __attribute__((ext_vector_type(4)));

// Soft-logic FP32 adder circuit, emulated exactly in integer arithmetic on the
// packed 32-bit word. Bit p in memory (p=0 sign, 1..8 exp MSB..LSB, 9..31 mant
// MSB..LSB) maps to IEEE bit (31-p) of the packed word.
// (Verified bit-exact vs reference in rounds 1-2: absmax 0.)
__device__ __forceinline__ uint32_t soft_fp32_add(uint32_t aw, uint32_t bw) {
    const uint32_t M28 = 0x0FFFFFFFu;
    uint32_t sa = aw >> 31, sb = bw >> 31;
    uint32_t ea = (aw >> 23) & 0xFFu, eb = (bw >> 23) & 0xFFu;
    uint32_t ma = aw & 0x7FFFFFu,     mb = bw & 0x7FFFFFu;
    uint32_t ha = (ea != 0u) ? 1u : 0u, hb = (eb != 0u) ? 1u : 0u;
    uint32_t eaf = ha ? ea : 1u;                 // effective exponent (subnormal -> 1)
    uint32_t ebf = hb ? eb : 1u;
    uint32_t mA = (ha << 27) | (ma << 4);        // 28-bit: hidden | mant | 4 guard zeros
    uint32_t mB = (hb << 27) | (mb << 4);
    // magnitude compare, lexicographic on (e_eff, hidden|mant)
    uint32_t keyA = (eaf << 24) | (ha << 23) | ma;
    uint32_t keyB = (ebf << 24) | (hb << 23) | mb;
    uint32_t age  = (keyA >= keyB) ? 1u : 0u;    // a_ge_b
    uint32_t abeq = (keyA == keyB) ? 1u : 0u;    // |A| == |B|
    uint32_t ediff = age ? (eaf - ebf) : (ebf - eaf);   // nonnegative by selection
    uint32_t big = (ediff >= 24u) ? 1u : 0u;     // is_big_diff
    uint32_t sh  = ediff & 31u;                  // shift_amt = low 5 bits
    uint32_t emax = age ? eaf : ebf;
    uint32_t ml   = age ? mA : mB;
    uint32_t msu  = age ? mB : mA;               // m_small unshifted
    uint32_t ms     = msu >> sh;
    uint32_t sticky = ((msu & ((1u << sh) - 1u)) != 0u) ? 1u : 0u;
    if (big) { ms = 0u; sticky = (msu != 0u) ? 1u : 0u; }
    uint32_t dsgn   = sa ^ sb;                   // is_diff_sign
    uint32_t cancel = dsgn & abeq;               // exact_cancel
    uint32_t sl     = age ? sa : sb;             // s_large
    uint32_t sum    = ml + ms;                   // 29-bit
    uint32_t scarry = sum >> 28;
    uint32_t sres   = sum & M28;
    uint32_t diff   = (ml - ms) & M28;
    uint32_t dfin   = (dsgn & sticky) ? ((diff - 1u) & M28) : diff;  // need_sub_one
    uint32_t mant   = dsgn ? dfin : sres;        // mant_res
    uint32_t rc     = dsgn ? 0u : scarry;        // result_carry
    uint32_t lzc    = mant ? (uint32_t)(__clz((int)mant) - 4) : 28u; // lzd28
    uint32_t undf   = (lzc >= emax) ? 1u : 0u;   // is_underflow
    uint32_t norm   = (mant << lzc) & M28;       // barrel_left
    uint32_t e_aft  = (emax - lzc) & 0xFFu;      // 8-bit wrap
    uint32_t e_p1   = (emax + 1u) & 0xFFu;
    uint32_t e_nrm  = undf ? 0u : e_aft;
    uint32_t fe     = rc ? e_p1 : e_nrm;         // final_e_pre
    uint32_t m_ovf  = mant >> 5;                 // bits 0..22  (also == m_subnorm)
    uint32_t r_ovf  = (mant >> 4) & 1u;          // bit 23
    uint32_t st_ovf = ((mant & 0xFu) != 0u) ? 1u : 0u;   // bits 24..27
    uint32_t m_nrm  = (norm >> 4) & 0x7FFFFFu;   // bits 1..23
    uint32_t r_nrm  = (norm >> 3) & 1u;          // bit 24
    uint32_t st_nrm = ((norm & 7u) != 0u) ? 1u : 0u;     // bits 25..27
    uint32_t m_pre  = rc ? m_ovf : m_nrm;
    uint32_t r_pre  = rc ? r_ovf : r_nrm;
    uint32_t st_pre = (rc ? st_ovf : st_nrm) | sticky;
    uint32_t m_sel  = undf ? m_ovf : m_pre;      // underflow -> truncated subnormal
    uint32_t Lb     = m_sel & 1u;
    uint32_t dor    = r_pre & (st_pre | Lb) & (undf ^ 1u);   // do_round (RNE)
    uint32_t mr     = m_sel + dor;               // 24-bit
    uint32_t rcar   = mr >> 23;                  // round_carry
    uint32_t m_fin  = mr & 0x7FFFFFu;
    uint32_t ce     = (fe + rcar) & 0xFFu;       // computed_e
    uint32_t os = cancel ? 0u : sl;
    uint32_t oe = cancel ? 0u : ce;
    uint32_t om = cancel ? 0u : m_fin;
    uint32_t ea1 = (ea == 0xFFu) ? 1u : 0u, eb1 = (eb == 0xFFu) ? 1u : 0u;
    uint32_t manz = (ma != 0u) ? 1u : 0u, mbnz = (mb != 0u) ? 1u : 0u;
    uint32_t anynan = (ea1 & manz) | (eb1 & mbnz);
    uint32_t ainf = ea1 & (manz ^ 1u);
    uint32_t binf = eb1 & (mbnz ^ 1u);
    uint32_t anyinf = ainf | binf;
    uint32_t isnan  = anynan | (dsgn & ainf & binf);
    uint32_t ovf    = (ce == 0xFFu) ? 1u : 0u;   // on computed_e, pre-cancel
    uint32_t out = (os << 31) | (oe << 23) | om;
    if (anyinf | ovf) out = (sl << 31) | (0xFFu << 23);   // inf_res
    if (isnan)        out = (0xFFu << 23) | 0x7FFFFFu;    // nan_res (sign=0)
    return out;
}

// One thread = one row for loads+compute (16 independent dwordx4 loads, deep
// MLP; L1 absorbs the 128-B stride since each wave consumes its whole 16 KB
// row-block). Store side transposed through 1 KB of LDS so global stores are
// fully coalesced f32x4 (round 2's per-thread strided 16-B stores caused 3.3x
// HBM write amplification via partial-line RMW).
__global__ __launch_bounds__(256) void SpikeFP32Adder_kernel(
    const uint32_t* __restrict__ A, const uint32_t* __restrict__ B,
    float* __restrict__ O, int nrows)
{
    const int t = threadIdx.x;
    const size_t rowIdx = (size_t)blockIdx.x * 256 + t;
    const size_t row = rowIdx < (size_t)nrows ? rowIdx : (size_t)nrows - 1; // clamp; all threads reach barrier

    const u32x4* Arow = (const u32x4*)(A + row * 32);
    const u32x4* Brow = (const u32x4*)(B + row * 32);

    u32x4 a[8], b[8];
    #pragma unroll
    for (int j = 0; j < 8; ++j) a[j] = Arow[j];
    #pragma unroll
    for (int j = 0; j < 8; ++j) b[j] = Brow[j];

    uint32_t aw = 0u, bw = 0u;
    #pragma unroll
    for (int j = 0; j < 8; ++j) {
        const int s = 31 - 4 * j;   // memory bit p=4j..4j+3 -> IEEE bit 31-p
        aw |= ((a[j].x >> 23) & 1u) << s;
        aw |= ((a[j].y >> 23) & 1u) << (s - 1);
        aw |= ((a[j].z >> 23) & 1u) << (s - 2);
        aw |= ((a[j].w >> 23) & 1u) << (s - 3);
        bw |= ((b[j].x >> 23) & 1u) << s;
        bw |= ((b[j].y >> 23) & 1u) << (s - 1);
        bw |= ((b[j].z >> 23) & 1u) << (s - 2);
        bw |= ((b[j].w >> 23) & 1u) << (s - 3);
    }

    uint32_t outw = soft_fp32_add(aw, bw);

    __shared__ uint32_t w_lds[256];
    w_lds[t] = outw;
    __syncthreads();

    // Coalesced expansion: iter it covers dwords [it*1024, it*1024+1024) of the
    // block's 8192-dword output chunk. Thread t writes dwords it*1024 + 4t..+3,
    // i.e. row (it*32 + t/8), cols 4*(t%8)..+3. 8 lanes share each LDS address
    // -> broadcast, conflict-free. Full-line nontemporal stores: no RMW, and
    // output doesn't evict the (re-read) inputs from L2/L3.
    const size_t chunkBase = (size_t)blockIdx.x * 8192;
    const size_t total = (size_t)nrows * 32;
    #pragma unroll
    for (int it = 0; it < 8; ++it) {
        uint32_t w = w_lds[it * 32 + (t >> 3)];
        const int c = 4 * (t & 7);
        f32x4 f;
        f.x = (float)((w >> (31 - c)) & 1u);
        f.y = (float)((w >> (30 - c)) & 1u);
        f.z = (float)((w >> (29 - c)) & 1u);
        f.w = (float)((w >> (28 - c)) & 1u);
        size_t idx = chunkBase + (size_t)it * 1024 + 4 * (size_t)t;
        if (idx + 3 < total)
            __builtin_nontemporal_store(f, (f32x4*)(O + idx));
    }
}

extern "C" void kernel_launch(void* const* d_in, const int* in_sizes, int n_in,
                              void* d_out, int out_size, void* d_ws, size_t ws_size,
                              hipStream_t stream) {
    const uint32_t* A = (const uint32_t*)d_in[0];
    const uint32_t* B = (const uint32_t*)d_in[1];
    float* O = (float*)d_out;
    int nrows = in_sizes[0] / 32;              // 524288
    int blocks = (nrows + 255) / 256;
    SpikeFP32Adder_kernel<<<dim3(blocks), dim3(256), 0, stream>>>(A, B, O, nrows);
}

// Round 4
// 34.039 us; speedup vs baseline: 4.3760x; 1.1011x over previous
//
#include <hip/hip_runtime.h>
#include <stdint.h>

typedef float    f32x4 __attribute__((ext_vector_type(4)));
typedef uint32_t u32x4 __attribute__((ext_vector_type(4)));

// Soft-logic FP32 adder circuit, emulated exactly in integer arithmetic on the
// packed 32-bit word. Bit p in memory (p=0 sign, 1..8 exp MSB..LSB, 9..31 mant
// MSB..LSB) maps to IEEE bit (31-p) of the packed word.
// (Verified bit-exact vs reference in rounds 1-3: absmax 0.)
__device__ __forceinline__ uint32_t soft_fp32_add(uint32_t aw, uint32_t bw) {
    const uint32_t M28 = 0x0FFFFFFFu;
    uint32_t sa = aw >> 31, sb = bw >> 31;
    uint32_t ea = (aw >> 23) & 0xFFu, eb = (bw >> 23) & 0xFFu;
    uint32_t ma = aw & 0x7FFFFFu,     mb = bw & 0x7FFFFFu;
    uint32_t ha = (ea != 0u) ? 1u : 0u, hb = (eb != 0u) ? 1u : 0u;
    uint32_t eaf = ha ? ea : 1u;                 // effective exponent (subnormal -> 1)
    uint32_t ebf = hb ? eb : 1u;
    uint32_t mA = (ha << 27) | (ma << 4);        // 28-bit: hidden | mant | 4 guard zeros
    uint32_t mB = (hb << 27) | (mb << 4);
    // magnitude compare, lexicographic on (e_eff, hidden|mant)
    uint32_t keyA = (eaf << 24) | (ha << 23) | ma;
    uint32_t keyB = (ebf << 24) | (hb << 23) | mb;
    uint32_t age  = (keyA >= keyB) ? 1u : 0u;    // a_ge_b
    uint32_t abeq = (keyA == keyB) ? 1u : 0u;    // |A| == |B|
    uint32_t ediff = age ? (eaf - ebf) : (ebf - eaf);   // nonnegative by selection
    uint32_t big = (ediff >= 24u) ? 1u : 0u;     // is_big_diff
    uint32_t sh  = ediff & 31u;                  // shift_amt = low 5 bits
    uint32_t emax = age ? eaf : ebf;
    uint32_t ml   = age ? mA : mB;
    uint32_t msu  = age ? mB : mA;               // m_small unshifted
    uint32_t ms     = msu >> sh;
    uint32_t sticky = ((msu & ((1u << sh) - 1u)) != 0u) ? 1u : 0u;
    if (big) { ms = 0u; sticky = (msu != 0u) ? 1u : 0u; }
    uint32_t dsgn   = sa ^ sb;                   // is_diff_sign
    uint32_t cancel = dsgn & abeq;               // exact_cancel
    uint32_t sl     = age ? sa : sb;             // s_large
    uint32_t sum    = ml + ms;                   // 29-bit
    uint32_t scarry = sum >> 28;
    uint32_t sres   = sum & M28;
    uint32_t diff   = (ml - ms) & M28;
    uint32_t dfin   = (dsgn & sticky) ? ((diff - 1u) & M28) : diff;  // need_sub_one
    uint32_t mant   = dsgn ? dfin : sres;        // mant_res
    uint32_t rc     = dsgn ? 0u : scarry;        // result_carry
    uint32_t lzc    = mant ? (uint32_t)(__clz((int)mant) - 4) : 28u; // lzd28
    uint32_t undf   = (lzc >= emax) ? 1u : 0u;   // is_underflow
    uint32_t norm   = (mant << lzc) & M28;       // barrel_left
    uint32_t e_aft  = (emax - lzc) & 0xFFu;      // 8-bit wrap
    uint32_t e_p1   = (emax + 1u) & 0xFFu;
    uint32_t e_nrm  = undf ? 0u : e_aft;
    uint32_t fe     = rc ? e_p1 : e_nrm;         // final_e_pre
    uint32_t m_ovf  = mant >> 5;                 // bits 0..22  (also == m_subnorm)
    uint32_t r_ovf  = (mant >> 4) & 1u;          // bit 23
    uint32_t st_ovf = ((mant & 0xFu) != 0u) ? 1u : 0u;   // bits 24..27
    uint32_t m_nrm  = (norm >> 4) & 0x7FFFFFu;   // bits 1..23
    uint32_t r_nrm  = (norm >> 3) & 1u;          // bit 24
    uint32_t st_nrm = ((norm & 7u) != 0u) ? 1u : 0u;     // bits 25..27
    uint32_t m_pre  = rc ? m_ovf : m_nrm;
    uint32_t r_pre  = rc ? r_ovf : r_nrm;
    uint32_t st_pre = (rc ? st_ovf : st_nrm) | sticky;
    uint32_t m_sel  = undf ? m_ovf : m_pre;      // underflow -> truncated subnormal
    uint32_t Lb     = m_sel & 1u;
    uint32_t dor    = r_pre & (st_pre | Lb) & (undf ^ 1u);   // do_round (RNE)
    uint32_t mr     = m_sel + dor;               // 24-bit
    uint32_t rcar   = mr >> 23;                  // round_carry
    uint32_t m_fin  = mr & 0x7FFFFFu;
    uint32_t ce     = (fe + rcar) & 0xFFu;       // computed_e
    uint32_t os = cancel ? 0u : sl;
    uint32_t oe = cancel ? 0u : ce;
    uint32_t om = cancel ? 0u : m_fin;
    uint32_t ea1 = (ea == 0xFFu) ? 1u : 0u, eb1 = (eb == 0xFFu) ? 1u : 0u;
    uint32_t manz = (ma != 0u) ? 1u : 0u, mbnz = (mb != 0u) ? 1u : 0u;
    uint32_t anynan = (ea1 & manz) | (eb1 & mbnz);
    uint32_t ainf = ea1 & (manz ^ 1u);
    uint32_t binf = eb1 & (mbnz ^ 1u);
    uint32_t anyinf = ainf | binf;
    uint32_t isnan  = anynan | (dsgn & ainf & binf);
    uint32_t ovf    = (ce == 0xFFu) ? 1u : 0u;   // on computed_e, pre-cancel
    uint32_t out = (os << 31) | (oe << 23) | om;
    if (anyinf | ovf) out = (sl << 31) | (0xFFu << 23);   // inf_res
    if (isnan)        out = (0xFFu << 23) | 0x7FFFFFu;    // nan_res (sign=0)
    return out;
}

// Fully coalesced BOTH directions.
// Load/pack: per iteration each thread loads one contiguous f32x4 (wave instr
// = 1 KB = 8 lines, vs round 3's 64-line scatter), extracts 4 bits into a
// partial word, and a 3-step __shfl_xor OR-butterfly over the 8-lane group
// assembles the full row word. Lane keeps iteration it == t%8, so thread t
// ends owning block-local row rho(t) = (t%8)*32 + t/8 (bijection; rows are
// independent, so the permuted assignment is free).
// Store: unchanged round-3 path (LDS indexed by actual row + coalesced f32x4
// nontemporal expansion; WRITE_SIZE verified exact 64 MiB).
__global__ __launch_bounds__(256) void SpikeFP32Adder_kernel(
    const uint32_t* __restrict__ A, const uint32_t* __restrict__ B,
    float* __restrict__ O, int nrows)
{
    const int t = threadIdx.x;
    const size_t total = (size_t)nrows * 32;
    const size_t chunkBase = (size_t)blockIdx.x * 8192;   // floats per 256-row block

    const int c = 4 * (t & 7);          // column base within the row this lane's nibble covers
    uint32_t aw = 0u, bw = 0u;

    #pragma unroll
    for (int it = 0; it < 8; ++it) {
        size_t idx = chunkBase + (size_t)it * 1024 + 4 * (size_t)t;
        size_t i2 = (idx + 3 < total) ? idx : (total - 4);   // clamp (BATCH%256==0 -> never taken)
        u32x4 av = *(const u32x4*)(A + i2);
        u32x4 bv = *(const u32x4*)(B + i2);

        uint32_t pa = (((av.x >> 23) & 1u) << (31 - c))
                    | (((av.y >> 23) & 1u) << (30 - c))
                    | (((av.z >> 23) & 1u) << (29 - c))
                    | (((av.w >> 23) & 1u) << (28 - c));
        uint32_t pb = (((bv.x >> 23) & 1u) << (31 - c))
                    | (((bv.y >> 23) & 1u) << (30 - c))
                    | (((bv.z >> 23) & 1u) << (29 - c))
                    | (((bv.w >> 23) & 1u) << (28 - c));

        // OR-reduce across the 8 lanes sharing this row (aligned groups).
        pa |= (uint32_t)__shfl_xor((int)pa, 1);
        pa |= (uint32_t)__shfl_xor((int)pa, 2);
        pa |= (uint32_t)__shfl_xor((int)pa, 4);
        pb |= (uint32_t)__shfl_xor((int)pb, 1);
        pb |= (uint32_t)__shfl_xor((int)pb, 2);
        pb |= (uint32_t)__shfl_xor((int)pb, 4);

        if ((t & 7) == it) { aw = pa; bw = pb; }
    }

    // This thread owns block-local row rho = (t%8)*32 + t/8.
    uint32_t outw = soft_fp32_add(aw, bw);

    __shared__ uint32_t w_lds[256];
    w_lds[((t & 7) << 5) | (t >> 3)] = outw;   // one 8-way-conflict ds_write; negligible
    __syncthreads();

    // Coalesced expansion (round-3 verified): iter it covers dwords
    // [it*1024, it*1024+1024) of the block's 8192-dword output chunk. Thread t
    // writes row (it*32 + t/8), cols 4*(t%8)..+3. 8 lanes share each LDS
    // address -> broadcast, conflict-free. Nontemporal full-line stores.
    #pragma unroll
    for (int it = 0; it < 8; ++it) {
        uint32_t w = w_lds[it * 32 + (t >> 3)];
        f32x4 f;
        f.x = (float)((w >> (31 - c)) & 1u);
        f.y = (float)((w >> (30 - c)) & 1u);
        f.z = (float)((w >> (29 - c)) & 1u);
        f.w = (float)((w >> (28 - c)) & 1u);
        size_t idx = chunkBase + (size_t)it * 1024 + 4 * (size_t)t;
        if (idx + 3 < total)
            __builtin_nontemporal_store(f, (f32x4*)(O + idx));
    }
}

extern "C" void kernel_launch(void* const* d_in, const int* in_sizes, int n_in,
                              void* d_out, int out_size, void* d_ws, size_t ws_size,
                              hipStream_t stream) {
    const uint32_t* A = (const uint32_t*)d_in[0];
    const uint32_t* B = (const uint32_t*)d_in[1];
    float* O = (float*)d_out;
    int nrows = in_sizes[0] / 32;              // 524288
    int blocks = (nrows + 255) / 256;
    SpikeFP32Adder_kernel<<<dim3(blocks), dim3(256), 0, stream>>>(A, B, O, nrows);
}